// Round 1
// baseline (373.822 us; speedup 1.0000x reference)
//
#include <hip/hip_runtime.h>

#define B_    4
#define HIMG  256
#define WIMG  256
#define C_    128
#define NH_   4
#define WS8   8
#define L_    64
#define NWX   32
#define TD_   100
#define NPATCH (HIMG*WIMG)           // 65536
#define TTOT  (NPATCH + 200)         // 65736
#define SCALE 0.17677669529663689f   // 32^-0.5

typedef __bf16 bf16x8 __attribute__((ext_vector_type(8)));
typedef __bf16 bf16x4 __attribute__((ext_vector_type(4)));
typedef float  f32x4  __attribute__((ext_vector_type(4)));

// workspace layout (bytes)
#define WS_WQ     0          // 384*128 bf16  = 98304
#define WS_WP     98304      // 128*128 bf16  = 32768
#define WS_BIAS   131072     // 4*64*64 f32   = 65536
#define WS_QKVTOK 196608     // 800*384 f32   = 1228800
#define WS_PXTOK  1425408    // 800*128 f32   = 409600
// total 1835008 bytes

// ---------------------------------------------------------------- prep
__global__ __launch_bounds__(256)
void prep_kernel(const float* __restrict__ Wq, const float* __restrict__ Wp,
                 const float* __restrict__ rel_table, const int* __restrict__ rel_index,
                 unsigned short* __restrict__ wq_b, unsigned short* __restrict__ wp_b,
                 float* __restrict__ biasT) {
    int id = blockIdx.x * 256 + threadIdx.x;
    if (id < 49152) {
        __bf16 v = (__bf16)Wq[id];
        wq_b[id] = *(unsigned short*)&v;
    } else if (id < 65536) {
        int i = id - 49152;
        __bf16 v = (__bf16)Wp[i];
        wp_b[i] = *(unsigned short*)&v;
    } else if (id < 81920) {
        int t = id - 65536;
        int h = t >> 12, ij = t & 4095;
        biasT[h * 4096 + ij] = rel_table[rel_index[ij] * 4 + h];
    }
}

// ---------------------------------------------------------------- fused window kernel
__global__ __launch_bounds__(256, 1)
void win_kernel(const float* __restrict__ x, const float* __restrict__ mask,
                const unsigned short* __restrict__ wq_u, const float* __restrict__ bqkv,
                const unsigned short* __restrict__ wp_u, const float* __restrict__ bproj,
                const float* __restrict__ biasT, float* __restrict__ out) {
    __shared__ __align__(16) __bf16 Qs[64 * 136];    // Q, later px
    __shared__ __align__(16) __bf16 Ks[64 * 136];
    __shared__ __align__(16) __bf16 VTs[128 * 72];   // V transposed [dim][token]
    __shared__ __align__(16) __bf16 Ps[4][64 * 72];  // per-wave P

    const __bf16* wq = (const __bf16*)wq_u;
    const __bf16* wp = (const __bf16*)wp_u;

    const int tid = threadIdx.x;
    const int w  = tid >> 6;          // wave == head
    const int l  = tid & 63;
    const int lo = l & 15;
    const int hi = l >> 4;
    const int bx = blockIdx.x;
    const int b  = bx >> 10;
    const int wi = (bx >> 5) & 31;
    const int wj = bx & 31;

    // ---------------- phase 1: QKV for this window (per-wave head-aligned cols)
    const float* xw = x + (((size_t)(b * HIMG) + wi * WS8) * WIMG + wj * WS8) * C_;
    const float* arow[4];
#pragma unroll
    for (int mt = 0; mt < 4; ++mt) {
        int t = mt * 16 + lo;
        arow[mt] = xw + ((size_t)(t >> 3) * WIMG + (t & 7)) * C_ + hi * 8;
    }
    int nbase[6];
    const __bf16* brow[6];
#pragma unroll
    for (int g = 0; g < 3; ++g) {
        nbase[2 * g]     = g * 128 + 32 * w;
        nbase[2 * g + 1] = g * 128 + 32 * w + 16;
    }
#pragma unroll
    for (int nt = 0; nt < 6; ++nt)
        brow[nt] = wq + (size_t)(nbase[nt] + lo) * C_ + hi * 8;

    f32x4 acc[4][6];
    const f32x4 zz = {0.f, 0.f, 0.f, 0.f};
#pragma unroll
    for (int mt = 0; mt < 4; ++mt)
#pragma unroll
        for (int nt = 0; nt < 6; ++nt) acc[mt][nt] = zz;

#pragma unroll
    for (int ks = 0; ks < 4; ++ks) {
        bf16x8 a[4], bb[6];
#pragma unroll
        for (int mt = 0; mt < 4; ++mt) {
            const float* pa = arow[mt] + ks * 32;
            float4 v0 = *(const float4*)pa;
            float4 v1 = *(const float4*)(pa + 4);
            bf16x8 av;
            av[0] = (__bf16)v0.x; av[1] = (__bf16)v0.y; av[2] = (__bf16)v0.z; av[3] = (__bf16)v0.w;
            av[4] = (__bf16)v1.x; av[5] = (__bf16)v1.y; av[6] = (__bf16)v1.z; av[7] = (__bf16)v1.w;
            a[mt] = av;
        }
#pragma unroll
        for (int nt = 0; nt < 6; ++nt)
            bb[nt] = *(const bf16x8*)(brow[nt] + ks * 32);
#pragma unroll
        for (int mt = 0; mt < 4; ++mt)
#pragma unroll
            for (int nt = 0; nt < 6; ++nt)
                acc[mt][nt] = __builtin_amdgcn_mfma_f32_16x16x32_bf16(a[mt], bb[nt], acc[mt][nt], 0, 0, 0);
    }

    // add b_qkv and scatter into LDS (Q, K row-major; V transposed)
#pragma unroll
    for (int nt = 0; nt < 6; ++nt) {
        float bq = bqkv[nbase[nt] + lo];
        int col = 32 * w + (nt & 1) * 16 + lo;
        if (nt < 2) {
#pragma unroll
            for (int mt = 0; mt < 4; ++mt)
#pragma unroll
                for (int r = 0; r < 4; ++r)
                    Qs[(mt * 16 + hi * 4 + r) * 136 + col] = (__bf16)(acc[mt][nt][r] + bq);
        } else if (nt < 4) {
#pragma unroll
            for (int mt = 0; mt < 4; ++mt)
#pragma unroll
                for (int r = 0; r < 4; ++r)
                    Ks[(mt * 16 + hi * 4 + r) * 136 + col] = (__bf16)(acc[mt][nt][r] + bq);
        } else {
#pragma unroll
            for (int mt = 0; mt < 4; ++mt) {
                bf16x4 vv;
#pragma unroll
                for (int r = 0; r < 4; ++r) vv[r] = (__bf16)(acc[mt][nt][r] + bq);
                *(bf16x4*)&VTs[col * 72 + mt * 16 + hi * 4] = vv;
            }
        }
    }
    // No barrier: each wave consumes only its own head's Q/K/VT slices.

    // ---------------- phase 2: attention (head w)
    f32x4 lg[4][4];
    {
        bf16x8 aq[4], bk[4];
#pragma unroll
        for (int mt = 0; mt < 4; ++mt)
            aq[mt] = *(const bf16x8*)&Qs[(mt * 16 + lo) * 136 + 32 * w + hi * 8];
#pragma unroll
        for (int nt = 0; nt < 4; ++nt)
            bk[nt] = *(const bf16x8*)&Ks[(nt * 16 + lo) * 136 + 32 * w + hi * 8];
#pragma unroll
        for (int mt = 0; mt < 4; ++mt)
#pragma unroll
            for (int nt = 0; nt < 4; ++nt)
                lg[mt][nt] = __builtin_amdgcn_mfma_f32_16x16x32_bf16(aq[mt], bk[nt], zz, 0, 0, 0);
    }

    const float* biasH = biasT + w * 4096;
    const float* maskW = mask + (size_t)(wi * NWX + wj) * 4096;
#pragma unroll
    for (int mt = 0; mt < 4; ++mt) {
#pragma unroll
        for (int r = 0; r < 4; ++r) {
            int row = mt * 16 + hi * 4 + r;
            float v[4];
            float m = -1e30f;
#pragma unroll
            for (int nt = 0; nt < 4; ++nt) {
                int col = nt * 16 + lo;
                float t = lg[mt][nt][r] * SCALE + biasH[row * 64 + col] + maskW[row * 64 + col];
                v[nt] = t;
                m = fmaxf(m, t);
            }
            m = fmaxf(m, __shfl_xor(m, 1));
            m = fmaxf(m, __shfl_xor(m, 2));
            m = fmaxf(m, __shfl_xor(m, 4));
            m = fmaxf(m, __shfl_xor(m, 8));
            float s = 0.f;
#pragma unroll
            for (int nt = 0; nt < 4; ++nt) { v[nt] = __expf(v[nt] - m); s += v[nt]; }
            s += __shfl_xor(s, 1);
            s += __shfl_xor(s, 2);
            s += __shfl_xor(s, 4);
            s += __shfl_xor(s, 8);
            float inv = 1.0f / s;
#pragma unroll
            for (int nt = 0; nt < 4; ++nt)
                Ps[w][row * 72 + nt * 16 + lo] = (__bf16)(v[nt] * inv);
        }
    }

    // PV
    f32x4 pv[4][2];
#pragma unroll
    for (int mt = 0; mt < 4; ++mt)
#pragma unroll
        for (int nt = 0; nt < 2; ++nt) pv[mt][nt] = zz;
#pragma unroll
    for (int ks = 0; ks < 2; ++ks) {
        bf16x8 ap[4], bv[2];
#pragma unroll
        for (int mt = 0; mt < 4; ++mt)
            ap[mt] = *(const bf16x8*)&Ps[w][(mt * 16 + lo) * 72 + ks * 32 + hi * 8];
#pragma unroll
        for (int nt = 0; nt < 2; ++nt)
            bv[nt] = *(const bf16x8*)&VTs[(32 * w + nt * 16 + lo) * 72 + ks * 32 + hi * 8];
#pragma unroll
        for (int mt = 0; mt < 4; ++mt)
#pragma unroll
            for (int nt = 0; nt < 2; ++nt)
                pv[mt][nt] = __builtin_amdgcn_mfma_f32_16x16x32_bf16(ap[mt], bv[nt], pv[mt][nt], 0, 0, 0);
    }
    // write px into Qs (own columns only)
#pragma unroll
    for (int mt = 0; mt < 4; ++mt)
#pragma unroll
        for (int nt = 0; nt < 2; ++nt)
#pragma unroll
            for (int r = 0; r < 4; ++r)
                Qs[(mt * 16 + hi * 4 + r) * 136 + 32 * w + nt * 16 + lo] = (__bf16)pv[mt][nt][r];

    __syncthreads();

    // ---------------- phase 3: proj (wave w -> out cols [32w, 32w+32))
    f32x4 po[4][2];
#pragma unroll
    for (int mt = 0; mt < 4; ++mt)
#pragma unroll
        for (int nt = 0; nt < 2; ++nt) po[mt][nt] = zz;
    const __bf16* wprow[2];
#pragma unroll
    for (int nt = 0; nt < 2; ++nt)
        wprow[nt] = wp + (size_t)(32 * w + nt * 16 + lo) * C_ + hi * 8;
#pragma unroll
    for (int ks = 0; ks < 4; ++ks) {
        bf16x8 apx[4], bw[2];
#pragma unroll
        for (int mt = 0; mt < 4; ++mt)
            apx[mt] = *(const bf16x8*)&Qs[(mt * 16 + lo) * 136 + ks * 32 + hi * 8];
#pragma unroll
        for (int nt = 0; nt < 2; ++nt)
            bw[nt] = *(const bf16x8*)(wprow[nt] + ks * 32);
#pragma unroll
        for (int mt = 0; mt < 4; ++mt)
#pragma unroll
            for (int nt = 0; nt < 2; ++nt)
                po[mt][nt] = __builtin_amdgcn_mfma_f32_16x16x32_bf16(apx[mt], bw[nt], po[mt][nt], 0, 0, 0);
    }
    float bp0 = bproj[32 * w + lo];
    float bp1 = bproj[32 * w + 16 + lo];
    float* outb = out + (size_t)b * TTOT * C_;
#pragma unroll
    for (int mt = 0; mt < 4; ++mt) {
#pragma unroll
        for (int r = 0; r < 4; ++r) {
            int row = mt * 16 + hi * 4 + r;
            int tok = (wi * 8 + (row >> 3)) * WIMG + wj * 8 + (row & 7);
            float* orow = outb + (size_t)tok * C_ + 32 * w + lo;
            orow[0]  = po[mt][0][r] + bp0;
            orow[16] = po[mt][1][r] + bp1;
        }
    }
}

// ---------------------------------------------------------------- token path (det/inter)
__global__ __launch_bounds__(256)
void tok_qkv_kernel(const float* __restrict__ det, const float* __restrict__ inter,
                    const float* __restrict__ Wq, const float* __restrict__ bq,
                    float* __restrict__ qkv_tok) {
    __shared__ float xs[128];
    int rid = blockIdx.x;                // 0..799
    int b = rid / 200, rem = rid % 200;
    const float* src = (rem < 100) ? det + (size_t)(b * 100 + rem) * 128
                                   : inter + (size_t)(b * 100 + rem - 100) * 128;
    int tid = threadIdx.x;
    if (tid < 128) xs[tid] = src[tid];
    __syncthreads();
    for (int n = tid; n < 384; n += 256) {
        const float* wr = Wq + (size_t)n * 128;
        float s = 0.f;
#pragma unroll 8
        for (int k = 0; k < 128; ++k) s += xs[k] * wr[k];
        qkv_tok[(size_t)rid * 384 + n] = s + bq[n];
    }
}

__global__ __launch_bounds__(256)
void tok_attn_kernel(const float* __restrict__ qkv_tok, float* __restrict__ px_tok) {
    __shared__ float qs[100 * 32];
    __shared__ float ks2[100 * 32];
    __shared__ float vs2[100 * 32];
    __shared__ float lg2[100 * 101];
    int bid = blockIdx.x;        // (b*2+set)*4 + h
    int h  = bid & 3;
    int bs = bid >> 2;           // 0..7
    int rid0 = bs * 100;
    int tid = threadIdx.x;
    for (int i = tid; i < 3200; i += 256) {
        int t = i >> 5, d = i & 31;
        const float* base = qkv_tok + (size_t)(rid0 + t) * 384 + 32 * h + d;
        qs[i]  = base[0];
        ks2[i] = base[128];
        vs2[i] = base[256];
    }
    __syncthreads();
    for (int idx = tid; idx < 10000; idx += 256) {
        int i = idx / 100, j = idx % 100;
        float s = 0.f;
#pragma unroll
        for (int d = 0; d < 32; ++d) s += qs[i * 32 + d] * ks2[j * 32 + d];
        lg2[i * 101 + j] = s * SCALE;
    }
    __syncthreads();
    if (tid < 100) {
        float m = -1e30f;
        for (int j = 0; j < 100; ++j) m = fmaxf(m, lg2[tid * 101 + j]);
        float s = 0.f;
        for (int j = 0; j < 100; ++j) {
            float e = __expf(lg2[tid * 101 + j] - m);
            lg2[tid * 101 + j] = e;
            s += e;
        }
        float inv = 1.0f / s;
        for (int j = 0; j < 100; ++j) lg2[tid * 101 + j] *= inv;
    }
    __syncthreads();
    for (int idx = tid; idx < 3200; idx += 256) {
        int i = idx >> 5, d = idx & 31;
        float s = 0.f;
        for (int j = 0; j < 100; ++j) s += lg2[i * 101 + j] * vs2[j * 32 + d];
        px_tok[(size_t)(rid0 + i) * 128 + 32 * h + d] = s;
    }
}

__global__ __launch_bounds__(256)
void tok_proj_kernel(const float* __restrict__ px_tok, const float* __restrict__ Wp,
                     const float* __restrict__ bp, float* __restrict__ out) {
    int gid = blockIdx.x * 256 + threadIdx.x;   // 0..102399
    int row = gid >> 7, c = gid & 127;
    int b = row / 200, rem = row % 200;
    const float* pr = px_tok + (size_t)row * 128;
    const float* wr = Wp + (size_t)c * 128;
    float s = 0.f;
#pragma unroll 8
    for (int k = 0; k < 128; ++k) s += pr[k] * wr[k];
    out[((size_t)b * TTOT + NPATCH + rem) * 128 + c] = s + bp[c];
}

// ---------------------------------------------------------------- launch
extern "C" void kernel_launch(void* const* d_in, const int* in_sizes, int n_in,
                              void* d_out, int out_size, void* d_ws, size_t ws_size,
                              hipStream_t stream) {
    const float* x         = (const float*)d_in[0];
    const float* det       = (const float*)d_in[1];
    const float* inter     = (const float*)d_in[2];
    const float* mask      = (const float*)d_in[3];
    const float* Wq        = (const float*)d_in[4];
    const float* bq        = (const float*)d_in[5];
    const float* Wp        = (const float*)d_in[6];
    const float* bp        = (const float*)d_in[7];
    const float* rel_table = (const float*)d_in[8];
    const int*   rel_index = (const int*)d_in[9];
    float* out = (float*)d_out;

    char* ws = (char*)d_ws;
    unsigned short* wq_b   = (unsigned short*)(ws + WS_WQ);
    unsigned short* wp_b   = (unsigned short*)(ws + WS_WP);
    float* biasT           = (float*)(ws + WS_BIAS);
    float* qkv_tok         = (float*)(ws + WS_QKVTOK);
    float* px_tok          = (float*)(ws + WS_PXTOK);

    prep_kernel<<<320, 256, 0, stream>>>(Wq, Wp, rel_table, rel_index, wq_b, wp_b, biasT);
    tok_qkv_kernel<<<800, 256, 0, stream>>>(det, inter, Wq, bq, qkv_tok);
    tok_attn_kernel<<<32, 256, 0, stream>>>(qkv_tok, px_tok);
    tok_proj_kernel<<<400, 256, 0, stream>>>(px_tok, Wp, bp, out);
    win_kernel<<<4096, 256, 0, stream>>>(x, mask, wq_b, bq, wp_b, bp, biasT, out);
}